// Round 5
// baseline (2336.249 us; speedup 1.0000x reference)
//
#include <hip/hip_runtime.h>

#define B 32
#define S 2048
#define I 256
#define H 256
#define MB 16          // batches per phase-2 block
#define LDH 264        // padded h row length in halves (528 B: 16B-aligned rows,
                       // bank stride 4c -> only free 2-way aliasing)

typedef _Float16 h2  __attribute__((ext_vector_type(2)));
typedef _Float16 h4  __attribute__((ext_vector_type(4)));
typedef _Float16 h8f __attribute__((ext_vector_type(8)));
typedef float    f4  __attribute__((ext_vector_type(4)));

// lgkm-only workgroup barrier: __syncthreads() drains vmcnt(0) before
// s_barrier; our per-step global ops are lane-private (each lane owns its
// (batch, n-columns) slice) so only LDS needs cross-wave visibility.
// imm 0xC07F = vmcnt(63) expcnt(7) lgkmcnt(0).
__device__ __forceinline__ void lds_barrier() {
    __asm__ __volatile__("" ::: "memory");
    __builtin_amdgcn_s_waitcnt(0xC07F);
    __builtin_amdgcn_s_barrier();
    __asm__ __volatile__("" ::: "memory");
}

__device__ __forceinline__ float fast_tanh(float x) {
    float e = __expf(2.0f * x);
    return 1.0f - __fdividef(2.0f, e + 1.0f);
}

// ---------------------------------------------------------------------------
// Phase 1: xw[m][n] = sum_k x[m][k]*Wxw[n][k] + Wxb[n]   (unchanged)
// ---------------------------------------------------------------------------
#define TM 64
#define TN 64
#define TK 32

__global__ __launch_bounds__(256) void phase1_gemm(
    const float* __restrict__ x, const float* __restrict__ Wxw,
    const float* __restrict__ Wxb, float* __restrict__ out)
{
    __shared__ __align__(16) float As[TK][TM + 4];
    __shared__ __align__(16) float Bs[TK][TN + 4];

    const int t  = threadIdx.x;
    const int tn = t & 15, tm = t >> 4;
    const int m0 = blockIdx.x * TM;
    const int n0 = blockIdx.y * TN;

    float acc[4][4] = {};
    float bias[4];
#pragma unroll
    for (int j = 0; j < 4; ++j) bias[j] = Wxb[n0 + 4 * tn + j];

    const int lr = t >> 3;
    const int lc = t & 7;

    for (int kt = 0; kt < I; kt += TK) {
#pragma unroll
        for (int hh = 0; hh < 2; ++hh) {
            const int m = lr + 32 * hh;
            float4 v = *(const float4*)(x   + (size_t)(m0 + m) * I + kt + 4 * lc);
            As[4 * lc + 0][m] = v.x; As[4 * lc + 1][m] = v.y;
            As[4 * lc + 2][m] = v.z; As[4 * lc + 3][m] = v.w;
            float4 w = *(const float4*)(Wxw + (size_t)(n0 + m) * I + kt + 4 * lc);
            Bs[4 * lc + 0][m] = w.x; Bs[4 * lc + 1][m] = w.y;
            Bs[4 * lc + 2][m] = w.z; Bs[4 * lc + 3][m] = w.w;
        }
        __syncthreads();
#pragma unroll
        for (int k = 0; k < TK; ++k) {
            float4 a = *(const float4*)&As[k][4 * tm];
            float4 b = *(const float4*)&Bs[k][4 * tn];
            float av[4] = {a.x, a.y, a.z, a.w};
            float bv[4] = {b.x, b.y, b.z, b.w};
#pragma unroll
            for (int i2 = 0; i2 < 4; ++i2)
#pragma unroll
                for (int j = 0; j < 4; ++j)
                    acc[i2][j] = fmaf(av[i2], bv[j], acc[i2][j]);
        }
        __syncthreads();
    }
#pragma unroll
    for (int i2 = 0; i2 < 4; ++i2) {
        float4 v = { acc[i2][0] + bias[0], acc[i2][1] + bias[1],
                     acc[i2][2] + bias[2], acc[i2][3] + bias[3] };
        *(float4*)(out + (size_t)(m0 + 4 * tm + i2) * H + n0 + 4 * tn) = v;
    }
}

// ---------------------------------------------------------------------------
// Phase 2 (MFMA): h_new[c][n] = tanh(xw[c][s][n] + sum_k Whw[n][k] h[c][k])
// as D = A*B + C with A = Whw (f16, persistent in regs), B[k][c] = h[c][k]
// (f16 in LDS, row-major per batch -> B-frag = one ds_read_b128), C seeded
// with xw (C/D col=lane&15 matches batch, 4 consecutive n rows per lane ->
// xw loads/stores are dwordx4).
// 2 blocks x 16 batches x 256 threads; wave w owns n in [64w, 64w+64).
// One lgkm-only barrier/step (h double-buffered), 2-deep xw prefetch.
// ---------------------------------------------------------------------------
__global__ __launch_bounds__(256, 1) void phase2_rnn(
    const float* __restrict__ Whw, float* __restrict__ out)
{
    __shared__ __align__(16) _Float16 hb[2][MB][LDH];

    const int t = threadIdx.x;
    const int w = t >> 6;          // wave -> n-range [64w, 64w+64)
    const int c = t & 15;          // lane&15: batch (for B/C/D) or n-row (for A)
    const int q = (t >> 4) & 3;    // quad within wave

    const int cg  = blockIdx.x * MB + c;   // global batch
    const int n00 = 64 * w + 4 * q;        // base n for this lane's D rows

    // --- A-fragments of Whw: wfrag[nt][kf], n = 64w+16nt+(lane&15),
    //     k = 32kf + 8q .. +7  (A[m=lane&15][k=quad*8+j]). Loaded once.
    h8f wfrag[4][8];
#pragma unroll
    for (int nt = 0; nt < 4; ++nt) {
        const float* wr = Whw + (size_t)(64 * w + 16 * nt + c) * H;
#pragma unroll
        for (int kf = 0; kf < 8; ++kf) {
            const float* p = wr + 32 * kf + 8 * q;
            f4 x0 = *(const f4*)(p);
            f4 x1 = *(const f4*)(p + 4);
            h8f f;
            f[0] = (_Float16)x0[0]; f[1] = (_Float16)x0[1];
            f[2] = (_Float16)x0[2]; f[3] = (_Float16)x0[3];
            f[4] = (_Float16)x1[0]; f[5] = (_Float16)x1[1];
            f[6] = (_Float16)x1[2]; f[7] = (_Float16)x1[3];
            wfrag[nt][kf] = f;
        }
    }

    // zero h buffer 0 (h starts at 0); one-time full barrier is fine
    for (int i = t; i < MB * LDH; i += 256) hb[0][0][i] = (_Float16)0;
    __syncthreads();

    float* ob = out + (size_t)cg * S * H;   // xw / outputs for batch cg

    // 2-deep xw prefetch. Reads up to 2 rows past s=S-1 land in the h_last
    // region of d_out (in bounds, values never used).
    f4 pf0[4], pf1[4];
#pragma unroll
    for (int nt = 0; nt < 4; ++nt) {
        pf0[nt] = *(const f4*)(ob + 0 * (size_t)H + n00 + 16 * nt);
        pf1[nt] = *(const f4*)(ob + 1 * (size_t)H + n00 + 16 * nt);
    }

    for (int s = 0; s < S; s += 2) {
        // ---------- even step s: read hb[0], write hb[1], xw in pf0 ----------
        {
            f4 acc[4];
#pragma unroll
            for (int nt = 0; nt < 4; ++nt) acc[nt] = pf0[nt];   // seed with xw
#pragma unroll
            for (int nt = 0; nt < 4; ++nt)                      // refill s+2
                pf0[nt] = *(const f4*)(ob + (size_t)(s + 2) * H + n00 + 16 * nt);
#pragma unroll
            for (int kf = 0; kf < 8; ++kf) {
                h8f bfrag = *(const h8f*)(&hb[0][c][32 * kf + 8 * q]);
#pragma unroll
                for (int nt = 0; nt < 4; ++nt)
                    acc[nt] = __builtin_amdgcn_mfma_f32_16x16x32_f16(
                        wfrag[nt][kf], bfrag, acc[nt], 0, 0, 0);
            }
#pragma unroll
            for (int nt = 0; nt < 4; ++nt) {
                f4 r;
#pragma unroll
                for (int i = 0; i < 4; ++i) r[i] = fast_tanh(acc[nt][i]);
                *(f4*)(ob + (size_t)s * H + n00 + 16 * nt) = r;  // outputs[c][s]
                h4 hh;
                hh[0] = (_Float16)r[0]; hh[1] = (_Float16)r[1];
                hh[2] = (_Float16)r[2]; hh[3] = (_Float16)r[3];
                *(h4*)(&hb[1][c][n00 + 16 * nt]) = hh;
            }
            lds_barrier();
        }
        // ---------- odd step s+1: read hb[1], write hb[0], xw in pf1 ---------
        {
            f4 acc[4];
#pragma unroll
            for (int nt = 0; nt < 4; ++nt) acc[nt] = pf1[nt];
#pragma unroll
            for (int nt = 0; nt < 4; ++nt)                      // refill s+3
                pf1[nt] = *(const f4*)(ob + (size_t)(s + 3) * H + n00 + 16 * nt);
#pragma unroll
            for (int kf = 0; kf < 8; ++kf) {
                h8f bfrag = *(const h8f*)(&hb[1][c][32 * kf + 8 * q]);
#pragma unroll
                for (int nt = 0; nt < 4; ++nt)
                    acc[nt] = __builtin_amdgcn_mfma_f32_16x16x32_f16(
                        wfrag[nt][kf], bfrag, acc[nt], 0, 0, 0);
            }
#pragma unroll
            for (int nt = 0; nt < 4; ++nt) {
                f4 r;
#pragma unroll
                for (int i = 0; i < 4; ++i) r[i] = fast_tanh(acc[nt][i]);
                *(f4*)(ob + (size_t)(s + 1) * H + n00 + 16 * nt) = r;
                h4 hh;
                hh[0] = (_Float16)r[0]; hh[1] = (_Float16)r[1];
                hh[2] = (_Float16)r[2]; hh[3] = (_Float16)r[3];
                *(h4*)(&hb[0][c][n00 + 16 * nt]) = hh;
                if (s + 1 == S - 1)                              // h_last
                    *(f4*)(out + (size_t)B * S * H + (size_t)cg * H
                           + n00 + 16 * nt) = r;
            }
            lds_barrier();
        }
    }
}

// ---------------------------------------------------------------------------
extern "C" void kernel_launch(void* const* d_in, const int* in_sizes, int n_in,
                              void* d_out, int out_size, void* d_ws, size_t ws_size,
                              hipStream_t stream) {
    const float* x   = (const float*)d_in[0];
    const float* Wxw = (const float*)d_in[1];
    const float* Wxb = (const float*)d_in[2];
    const float* Whw = (const float*)d_in[3];
    float* out = (float*)d_out;

    dim3 g1(B * S / TM, H / TN);   // 1024 x 4
    phase1_gemm<<<g1, 256, 0, stream>>>(x, Wxw, Wxb, out);
    phase2_rnn<<<B / MB, 256, 0, stream>>>(Whw, out);
}